// Round 1
// 113.407 us; speedup vs baseline: 1.1221x; 1.1221x over previous
//
#include <hip/hip_runtime.h>

// STFT: x[16, 262144] fp32, Hann 2048, hop 512, reflect pad 1024.
// Output: real[16,1025,513] ++ imag[16,1025,513], fp32.
//
// Round 8: latency-hiding restructure. R7 counters showed all pipes idle
// (VALUBusy 23%, HBM 25%, occupancy 32%) with 1 block/CU (148.5 KB LDS) and 5
// workgroup-wide barriers => phase latencies (global load -> 4 LDS/VALU FFT
// phases -> scattered store) were fully serialized. This round:
//  - Block halved: 512 threads, 4 packed FFTs (8 frames), LDS 67.6 KB
//    -> 2 resident blocks/CU, so one block's FFT compute overlaps the
//    sibling's global loads and store tail. Per-thread work per phase is
//    unchanged (loader 16 iters, octet 2, quad 4, epilogue 4).
//  - Grid 1040 = 16x64 main + 16 tail blocks (frame 512, phantom-packed).
//  - XCD swizzle extended pairs->quads: g..g+3 (32 B row chunks forming one
//    128 B span) land on the same XCD in adjacent slots so L2 still merges
//    partial-line writes.
//  - Epilogue items are (k, half): 4 LDS reads -> 8 stores, lanes cluster
//    32 rows x 32 B per wave instead of 64 rows x 4 B scatter.
//  - FFT core identical to R7: 3 radix-8 octet passes + 1 radix-4 quad pass,
//    twiddles via __sincosf.

#define N_FFT   2048
#define LOG2N   11
#define HOP     512
#define PADL    1024
#define NBINS   1025
#define NFRAMES 513
#define NBATCH  16
#define TLEN    262144

#define HALF_OUT ((size_t)NBATCH * NBINS * NFRAMES)   // 8,413,200 floats per plane

__device__ __forceinline__ int pidx(int a) { return a + (a >> 5); }

__device__ __forceinline__ int refl(int j) {
    if (j < 0)          j = -j;
    else if (j >= TLEN) j = 2 * TLEN - 2 - j;
    return j;
}

__device__ __forceinline__ float2 cmul(float2 a, float2 w) {
    return make_float2(fmaf(a.x, w.x, -a.y * w.y), fmaf(a.x, w.y, a.y * w.x));
}
__device__ __forceinline__ float2 cadd(float2 a, float2 b) {
    return make_float2(a.x + b.x, a.y + b.y);
}
__device__ __forceinline__ float2 csub(float2 a, float2 b) {
    return make_float2(a.x - b.x, a.y - b.y);
}
__device__ __forceinline__ float2 csqr(float2 w) {
    return make_float2(fmaf(w.x, w.x, -w.y * w.y), 2.0f * w.x * w.y);
}

// Three DIT stages (halves H, 2H, 4H) on points base + m*H, m=0..7, in registers.
template <int H, int L2H>
__device__ __forceinline__ void octet_pass(float2* __restrict__ zc, int q) {
    const int p    = q & (H - 1);
    const int base = ((q >> L2H) << (L2H + 3)) + p;
    int ia[8];
#pragma unroll
    for (int m = 0; m < 8; ++m) ia[m] = pidx(base + m * H);
    float2 v0 = zc[ia[0]], v1 = zc[ia[1]], v2 = zc[ia[2]], v3 = zc[ia[3]];
    float2 v4 = zc[ia[4]], v5 = zc[ia[5]], v6 = zc[ia[6]], v7 = zc[ia[7]];

    float2 w1, w2, w3;
    if (H == 1) {
        w3 = make_float2(1.0f, 0.0f); w2 = w3; w1 = w3;   // p==0 always
    } else {
        float s, c;
        __sincosf((float)p * (-3.14159265358979323846f / (4.0f * (float)H)), &s, &c);
        w3 = make_float2(c, s);
        w2 = csqr(w3);
        w1 = csqr(w2);
    }

    float2 t;
    // stage A (half=H): pairs (0,1)(2,3)(4,5)(6,7), all twiddle w1
    t = cmul(v1, w1); v1 = csub(v0, t); v0 = cadd(v0, t);
    t = cmul(v3, w1); v3 = csub(v2, t); v2 = cadd(v2, t);
    t = cmul(v5, w1); v5 = csub(v4, t); v4 = cadd(v4, t);
    t = cmul(v7, w1); v7 = csub(v6, t); v6 = cadd(v6, t);
    // stage B (half=2H): pairs (0,2)(4,6) w2 ; (1,3)(5,7) -i*w2
    const float2 w2m = make_float2(w2.y, -w2.x);
    t = cmul(v2, w2);  v2 = csub(v0, t); v0 = cadd(v0, t);
    t = cmul(v3, w2m); v3 = csub(v1, t); v1 = cadd(v1, t);
    t = cmul(v6, w2);  v6 = csub(v4, t); v4 = cadd(v4, t);
    t = cmul(v7, w2m); v7 = csub(v5, t); v5 = cadd(v5, t);
    // stage C (half=4H): pairs (0,4) w3 ; (1,5) w3*e^{-i pi/4} ; (2,6) -i*w3 ; (3,7) -i*w3*e^{-i pi/4}
    const float R = 0.70710678118654752f;
    const float2 w3o  = make_float2((w3.x + w3.y) * R, (w3.y - w3.x) * R);
    const float2 w3m  = make_float2(w3.y, -w3.x);
    const float2 w3mo = make_float2(w3o.y, -w3o.x);
    t = cmul(v4, w3);   v4 = csub(v0, t); v0 = cadd(v0, t);
    t = cmul(v5, w3o);  v5 = csub(v1, t); v1 = cadd(v1, t);
    t = cmul(v6, w3m);  v6 = csub(v2, t); v2 = cadd(v2, t);
    t = cmul(v7, w3mo); v7 = csub(v3, t); v3 = cadd(v3, t);

    zc[ia[0]] = v0; zc[ia[1]] = v1; zc[ia[2]] = v2; zc[ia[3]] = v3;
    zc[ia[4]] = v4; zc[ia[5]] = v5; zc[ia[6]] = v6; zc[ia[7]] = v7;
}

__global__ __launch_bounds__(512, 4) void stft_one(
    const float* __restrict__ x,
    const float* __restrict__ window,
    float* __restrict__ out)
{
    __shared__ float2 z[4][2113];     // 4 packed FFTs, 67,616 B -> 2 blocks/CU

    // Block id mapping: d in [0,1024) covers (b, g) for g in [0,64); quads of
    // consecutive g (same 128 B output-line span) get ids differing by 8
    // (same XCD under round-robin) in adjacent slots (co-resident in time).
    // d in [1024,1040): tail blocks, one per batch, frame 512 only.
    const int d = blockIdx.x;
    int b, g;
    if (d >= 1024) {
        b = d - 1024;
        g = 64;
    } else {
        const int xcd  = d & 7;
        const int slot = d >> 3;                  // [0,128)
        const int Q    = (slot >> 2) * 8 + xcd;   // quad id [0,256)
        const int L    = Q * 4 + (slot & 3);      // logical block [0,1024)
        b = L >> 6;
        g = L & 63;
    }
    const int tid = threadIdx.x;
    const int f0  = g * 8;
    const int npl = (g == 64) ? 1 : 4;            // planes (packed FFTs)

    // ---- load npl*2 windowed frames, bit-reversed ----
    const float* xb = x + (size_t)b * TLEN;
    for (int idx = tid; idx < npl * 2048; idx += 512) {
        const int c  = idx >> 11;
        const int n  = idx & 2047;
        const int fa = f0 + 2 * c;
        const float w  = window[n];
        const float va = xb[refl(fa * HOP - PADL + n)] * w;
        const float vb = xb[refl((fa + 1) * HOP - PADL + n)] * w;  // phantom frame ok
        const int r = (int)(__brev((unsigned)n) >> (32 - LOG2N));
        z[c][pidx(r)] = make_float2(va, vb);
    }
    __syncthreads();

    // ---- stages 1-3 (h=1), 4-6 (h=8), 7-9 (h=64): radix-8 register passes ----
    for (int idx = tid; idx < npl * 256; idx += 512)
        octet_pass<1, 0>(z[idx >> 8], idx & 255);
    __syncthreads();
    for (int idx = tid; idx < npl * 256; idx += 512)
        octet_pass<8, 3>(z[idx >> 8], idx & 255);
    __syncthreads();
    for (int idx = tid; idx < npl * 256; idx += 512)
        octet_pass<64, 6>(z[idx >> 8], idx & 255);
    __syncthreads();

    // ---- stages 10-11: radix-4 quad pass (h=512) ----
    for (int idx = tid; idx < npl * 512; idx += 512) {
        const int c = idx >> 9;
        const int p = idx & 511;
        float s, cc;
        __sincosf((float)p * (-3.14159265358979323846f / 1024.0f), &s, &cc);
        const float2 w2  = make_float2(cc, s);        // exp(-i*pi*p/1024)
        const float2 w1  = csqr(w2);                  // exp(-i*pi*p/512)
        const float2 w2m = make_float2(w2.y, -w2.x);  // -i*w2
        const int i0 = pidx(p), i1 = pidx(p + 512), i2 = pidx(p + 1024), i3 = pidx(p + 1536);
        float2 v0 = z[c][i0], v1 = z[c][i1], v2 = z[c][i2], v3 = z[c][i3];
        float2 t;
        // half=512: pairs (0,1)(2,3), twiddle w1
        t = cmul(v1, w1); v1 = csub(v0, t); v0 = cadd(v0, t);
        t = cmul(v3, w1); v3 = csub(v2, t); v2 = cadd(v2, t);
        // half=1024: pair (0,2) w2 ; pair (1,3) -i*w2
        t = cmul(v2, w2);  v2 = csub(v0, t); v0 = cadd(v0, t);
        t = cmul(v3, w2m); v3 = csub(v1, t); v1 = cadd(v1, t);
        z[c][i0] = v0; z[c][i1] = v1; z[c][i2] = v2; z[c][i3] = v3;
    }
    __syncthreads();

    // ---- unpack + direct write ----
    float* __restrict__ outr = out;
    float* __restrict__ outi = out + HALF_OUT;
    if (g < 64) {
        // item = (k, h): planes 2h, 2h+1 -> frames f0+4h .. f0+4h+3.
        // A wave covers 32 consecutive k (rows) x 2 halves: 32 B per row.
        for (int idx = tid; idx < 2 * NBINS; idx += 512) {
            const int k  = idx >> 1;
            const int h  = idx & 1;
            const int km = (N_FFT - k) & (N_FFT - 1);
            const float2 zk0 = z[2 * h][pidx(k)];
            const float2 zr0 = z[2 * h][pidx(km)];
            const float2 zk1 = z[2 * h + 1][pidx(k)];
            const float2 zr1 = z[2 * h + 1][pidx(km)];
            const size_t o = ((size_t)b * NBINS + (size_t)k) * NFRAMES
                           + (size_t)(f0 + 4 * h);
            outr[o + 0] = 0.5f * (zk0.x + zr0.x);   // even frame re
            outr[o + 1] = 0.5f * (zk0.y + zr0.y);   // odd frame re
            outr[o + 2] = 0.5f * (zk1.x + zr1.x);
            outr[o + 3] = 0.5f * (zk1.y + zr1.y);
            outi[o + 0] = 0.5f * (zk0.y - zr0.y);   // even frame im
            outi[o + 1] = 0.5f * (zr0.x - zk0.x);   // odd frame im
            outi[o + 2] = 0.5f * (zk1.y - zr1.y);
            outi[o + 3] = 0.5f * (zr1.x - zk1.x);
        }
    } else {
        // tail: frame 512 is the real part of the single packed FFT
        for (int k = tid; k < NBINS; k += 512) {
            const int km = (N_FFT - k) & (N_FFT - 1);
            const float2 zk = z[0][pidx(k)];
            const float2 zr = z[0][pidx(km)];
            const size_t o = ((size_t)b * NBINS + (size_t)k) * NFRAMES + 512;
            outr[o] = 0.5f * (zk.x + zr.x);
            outi[o] = 0.5f * (zk.y - zr.y);
        }
    }
}

extern "C" void kernel_launch(void* const* d_in, const int* in_sizes, int n_in,
                              void* d_out, int out_size, void* d_ws, size_t ws_size,
                              hipStream_t stream) {
    const float* x      = (const float*)d_in[0];
    const float* window = (const float*)d_in[1];
    float* out          = (float*)d_out;

    dim3 grid(1040);   // 1024 main + 16 tail blocks; d_ws deliberately unused
    stft_one<<<grid, 512, 0, stream>>>(x, window, out);
}

// Round 2
// 108.613 us; speedup vs baseline: 1.1717x; 1.0441x over previous
//
#include <hip/hip_runtime.h>

// STFT: x[16, 262144] fp32, Hann 2048, hop 512, reflect pad 1024.
// Output: real[16,1025,513] ++ imag[16,1025,513], fp32.
//
// Round 9: occupancy doubling, same structure as R8. R8 counters still showed
// all pipes idle (VALUBusy 30%, HBM 25%, occupancy 30%) => still latency-bound
// with 2 blocks/CU. This round:
//  - Block: 512 threads, 2 packed FFTs (4 frames), LDS float2 z[2][2113]
//    = 33.8 KB -> 4 blocks/CU = 32 waves/CU (full wave capacity), 4
//    independent barrier domains per CU. __launch_bounds__(512,8) (VGPR 52
//    fits the <=64 budget).
//  - Grid 2064 = 16x128 main + 16 tail blocks (frame 512, phantom-packed).
//  - XCD swizzle extended quads->octets: 8 consecutive g (16 B row chunks
//    forming one full 128 B line span) land on the same XCD in adjacent
//    slots so L2 merges the partial-line writes (mechanism verified in R8:
//    WRITE_SIZE 124->94 MB).
//  - FFT core identical: 3 radix-8 octet passes + 1 radix-4 quad pass,
//    twiddles via __sincosf; per-thread per-phase work halved.

#define N_FFT   2048
#define LOG2N   11
#define HOP     512
#define PADL    1024
#define NBINS   1025
#define NFRAMES 513
#define NBATCH  16
#define TLEN    262144

#define HALF_OUT ((size_t)NBATCH * NBINS * NFRAMES)   // 8,413,200 floats per plane

__device__ __forceinline__ int pidx(int a) { return a + (a >> 5); }

__device__ __forceinline__ int refl(int j) {
    if (j < 0)          j = -j;
    else if (j >= TLEN) j = 2 * TLEN - 2 - j;
    return j;
}

__device__ __forceinline__ float2 cmul(float2 a, float2 w) {
    return make_float2(fmaf(a.x, w.x, -a.y * w.y), fmaf(a.x, w.y, a.y * w.x));
}
__device__ __forceinline__ float2 cadd(float2 a, float2 b) {
    return make_float2(a.x + b.x, a.y + b.y);
}
__device__ __forceinline__ float2 csub(float2 a, float2 b) {
    return make_float2(a.x - b.x, a.y - b.y);
}
__device__ __forceinline__ float2 csqr(float2 w) {
    return make_float2(fmaf(w.x, w.x, -w.y * w.y), 2.0f * w.x * w.y);
}

// Three DIT stages (halves H, 2H, 4H) on points base + m*H, m=0..7, in registers.
template <int H, int L2H>
__device__ __forceinline__ void octet_pass(float2* __restrict__ zc, int q) {
    const int p    = q & (H - 1);
    const int base = ((q >> L2H) << (L2H + 3)) + p;
    int ia[8];
#pragma unroll
    for (int m = 0; m < 8; ++m) ia[m] = pidx(base + m * H);
    float2 v0 = zc[ia[0]], v1 = zc[ia[1]], v2 = zc[ia[2]], v3 = zc[ia[3]];
    float2 v4 = zc[ia[4]], v5 = zc[ia[5]], v6 = zc[ia[6]], v7 = zc[ia[7]];

    float2 w1, w2, w3;
    if (H == 1) {
        w3 = make_float2(1.0f, 0.0f); w2 = w3; w1 = w3;   // p==0 always
    } else {
        float s, c;
        __sincosf((float)p * (-3.14159265358979323846f / (4.0f * (float)H)), &s, &c);
        w3 = make_float2(c, s);
        w2 = csqr(w3);
        w1 = csqr(w2);
    }

    float2 t;
    // stage A (half=H): pairs (0,1)(2,3)(4,5)(6,7), all twiddle w1
    t = cmul(v1, w1); v1 = csub(v0, t); v0 = cadd(v0, t);
    t = cmul(v3, w1); v3 = csub(v2, t); v2 = cadd(v2, t);
    t = cmul(v5, w1); v5 = csub(v4, t); v4 = cadd(v4, t);
    t = cmul(v7, w1); v7 = csub(v6, t); v6 = cadd(v6, t);
    // stage B (half=2H): pairs (0,2)(4,6) w2 ; (1,3)(5,7) -i*w2
    const float2 w2m = make_float2(w2.y, -w2.x);
    t = cmul(v2, w2);  v2 = csub(v0, t); v0 = cadd(v0, t);
    t = cmul(v3, w2m); v3 = csub(v1, t); v1 = cadd(v1, t);
    t = cmul(v6, w2);  v6 = csub(v4, t); v4 = cadd(v4, t);
    t = cmul(v7, w2m); v7 = csub(v5, t); v5 = cadd(v5, t);
    // stage C (half=4H): pairs (0,4) w3 ; (1,5) w3*e^{-i pi/4} ; (2,6) -i*w3 ; (3,7) -i*w3*e^{-i pi/4}
    const float R = 0.70710678118654752f;
    const float2 w3o  = make_float2((w3.x + w3.y) * R, (w3.y - w3.x) * R);
    const float2 w3m  = make_float2(w3.y, -w3.x);
    const float2 w3mo = make_float2(w3o.y, -w3o.x);
    t = cmul(v4, w3);   v4 = csub(v0, t); v0 = cadd(v0, t);
    t = cmul(v5, w3o);  v5 = csub(v1, t); v1 = cadd(v1, t);
    t = cmul(v6, w3m);  v6 = csub(v2, t); v2 = cadd(v2, t);
    t = cmul(v7, w3mo); v7 = csub(v3, t); v3 = cadd(v3, t);

    zc[ia[0]] = v0; zc[ia[1]] = v1; zc[ia[2]] = v2; zc[ia[3]] = v3;
    zc[ia[4]] = v4; zc[ia[5]] = v5; zc[ia[6]] = v6; zc[ia[7]] = v7;
}

__global__ __launch_bounds__(512, 8) void stft_one(
    const float* __restrict__ x,
    const float* __restrict__ window,
    float* __restrict__ out)
{
    __shared__ float2 z[2][2113];     // 2 packed FFTs, 33,808 B -> 4 blocks/CU

    // Block id mapping: d in [0,2048) covers (b, g) for g in [0,128); octets
    // of consecutive g (one 128 B output-line span) get ids differing by 8
    // (same XCD under round-robin) in adjacent slots (co-resident in time).
    // d in [2048,2064): tail blocks, one per batch, frame 512 only.
    const int d = blockIdx.x;
    int b, g;
    if (d >= 2048) {
        b = d - 2048;
        g = 128;
    } else {
        const int xcd  = d & 7;
        const int slot = d >> 3;                  // [0,256)
        const int O    = (slot >> 3) * 8 + xcd;   // octet id [0,256)
        const int L    = O * 8 + (slot & 7);      // logical block [0,2048)
        b = L >> 7;
        g = L & 127;
    }
    const int tid = threadIdx.x;
    const int f0  = g * 4;
    const int npl = (g == 128) ? 1 : 2;           // planes (packed FFTs)

    // ---- load npl*2 windowed frames, bit-reversed ----
    const float* xb = x + (size_t)b * TLEN;
    for (int idx = tid; idx < npl * 2048; idx += 512) {
        const int c  = idx >> 11;
        const int n  = idx & 2047;
        const int fa = f0 + 2 * c;
        const float w  = window[n];
        const float va = xb[refl(fa * HOP - PADL + n)] * w;
        const float vb = xb[refl((fa + 1) * HOP - PADL + n)] * w;  // phantom frame ok
        const int r = (int)(__brev((unsigned)n) >> (32 - LOG2N));
        z[c][pidx(r)] = make_float2(va, vb);
    }
    __syncthreads();

    // ---- stages 1-3 (h=1), 4-6 (h=8), 7-9 (h=64): radix-8 register passes ----
    for (int idx = tid; idx < npl * 256; idx += 512)
        octet_pass<1, 0>(z[idx >> 8], idx & 255);
    __syncthreads();
    for (int idx = tid; idx < npl * 256; idx += 512)
        octet_pass<8, 3>(z[idx >> 8], idx & 255);
    __syncthreads();
    for (int idx = tid; idx < npl * 256; idx += 512)
        octet_pass<64, 6>(z[idx >> 8], idx & 255);
    __syncthreads();

    // ---- stages 10-11: radix-4 quad pass (h=512) ----
    for (int idx = tid; idx < npl * 512; idx += 512) {
        const int c = idx >> 9;
        const int p = idx & 511;
        float s, cc;
        __sincosf((float)p * (-3.14159265358979323846f / 1024.0f), &s, &cc);
        const float2 w2  = make_float2(cc, s);        // exp(-i*pi*p/1024)
        const float2 w1  = csqr(w2);                  // exp(-i*pi*p/512)
        const float2 w2m = make_float2(w2.y, -w2.x);  // -i*w2
        const int i0 = pidx(p), i1 = pidx(p + 512), i2 = pidx(p + 1024), i3 = pidx(p + 1536);
        float2 v0 = z[c][i0], v1 = z[c][i1], v2 = z[c][i2], v3 = z[c][i3];
        float2 t;
        // half=512: pairs (0,1)(2,3), twiddle w1
        t = cmul(v1, w1); v1 = csub(v0, t); v0 = cadd(v0, t);
        t = cmul(v3, w1); v3 = csub(v2, t); v2 = cadd(v2, t);
        // half=1024: pair (0,2) w2 ; pair (1,3) -i*w2
        t = cmul(v2, w2);  v2 = csub(v0, t); v0 = cadd(v0, t);
        t = cmul(v3, w2m); v3 = csub(v1, t); v1 = cadd(v1, t);
        z[c][i0] = v0; z[c][i1] = v1; z[c][i2] = v2; z[c][i3] = v3;
    }
    __syncthreads();

    // ---- unpack + direct write ----
    float* __restrict__ outr = out;
    float* __restrict__ outi = out + HALF_OUT;
    if (g < 128) {
        // planes 0,1 -> frames f0..f0+3; 16 B chunk per row; a wave covers
        // 64 consecutive k rows. Octet-swizzle makes the other 7 chunks of
        // each 128 B line co-resident on the same XCD.
        for (int k = tid; k < NBINS; k += 512) {
            const int km = (N_FFT - k) & (N_FFT - 1);
            const float2 zk0 = z[0][pidx(k)];
            const float2 zr0 = z[0][pidx(km)];
            const float2 zk1 = z[1][pidx(k)];
            const float2 zr1 = z[1][pidx(km)];
            const size_t o = ((size_t)b * NBINS + (size_t)k) * NFRAMES + (size_t)f0;
            outr[o + 0] = 0.5f * (zk0.x + zr0.x);   // even frame re
            outr[o + 1] = 0.5f * (zk0.y + zr0.y);   // odd frame re
            outr[o + 2] = 0.5f * (zk1.x + zr1.x);
            outr[o + 3] = 0.5f * (zk1.y + zr1.y);
            outi[o + 0] = 0.5f * (zk0.y - zr0.y);   // even frame im
            outi[o + 1] = 0.5f * (zr0.x - zk0.x);   // odd frame im
            outi[o + 2] = 0.5f * (zk1.y - zr1.y);
            outi[o + 3] = 0.5f * (zr1.x - zk1.x);
        }
    } else {
        // tail: frame 512 is the real part of the single packed FFT
        for (int k = tid; k < NBINS; k += 512) {
            const int km = (N_FFT - k) & (N_FFT - 1);
            const float2 zk = z[0][pidx(k)];
            const float2 zr = z[0][pidx(km)];
            const size_t o = ((size_t)b * NBINS + (size_t)k) * NFRAMES + 512;
            outr[o] = 0.5f * (zk.x + zr.x);
            outi[o] = 0.5f * (zk.y - zr.y);
        }
    }
}

extern "C" void kernel_launch(void* const* d_in, const int* in_sizes, int n_in,
                              void* d_out, int out_size, void* d_ws, size_t ws_size,
                              hipStream_t stream) {
    const float* x      = (const float*)d_in[0];
    const float* window = (const float*)d_in[1];
    float* out          = (float*)d_out;

    dim3 grid(2064);   // 2048 main + 16 tail blocks; d_ws deliberately unused
    stft_one<<<grid, 512, 0, stream>>>(x, window, out);
}